// Round 14
// baseline (303.429 us; speedup 1.0000x reference)
//
#include <hip/hip_runtime.h>
#include <hip/hip_fp16.h>
#include <hip/hip_fp8.h>

#define IN_CH  128
#define HID_CH 64
#define OUT_CH 8
#define BSH    8        // 256 nodes per bucket
#define BCAP   8960     // per-bucket edge capacity
#define PCHUNK 8192     // edges per partition block

typedef unsigned long long ull;

// edge_index arrives as int32. src = ei[0..E), dst = ei[E..2E).
// packed edge: low bits = src (fits 17 bits), bits 24..31 = dst & 255

__device__ __forceinline__ unsigned char f2fp8(float f) {
    __hip_fp8_e4m3 t(f);
    return (unsigned char)t.__x;
}
__device__ __forceinline__ float fp82f(unsigned char b) {
    __hip_fp8_e4m3 t;
    t.__x = (__hip_fp8_storage_t)b;
    return (float)t;
}

// ---------- 1. coarse partition into 256-node buckets (dense-run writes) ----------
__global__ __launch_bounds__(512) void part_k(const int* __restrict__ ei, int E, int NB,
                                              int* __restrict__ gcnt,
                                              unsigned* __restrict__ bucket) {
    __shared__ int cnt[512];
    __shared__ int scn[512];
    __shared__ int gbase[512];
    __shared__ unsigned ordered[PCHUNK];    // 32 KB
    int t = threadIdx.x;
    int c0 = blockIdx.x * PCHUNK;
    const int* __restrict__ src = ei;
    const int* __restrict__ dst = ei + E;

    cnt[t] = 0;
    __syncthreads();
    for (int i = t; i < PCHUNK; i += 512) {
        int e = c0 + i;
        if (e < E) atomicAdd(&cnt[dst[e] >> BSH], 1);
    }
    __syncthreads();
    scn[t] = cnt[t];
    __syncthreads();
    for (int o = 1; o < 512; o <<= 1) {
        int v = (t >= o) ? scn[t - o] : 0;
        __syncthreads();
        scn[t] += v;
        __syncthreads();
    }
    int ex = scn[t] - cnt[t];
    __syncthreads();
    scn[t] = ex;                             // exclusive scan
    int cn = cnt[t];
    gbase[t] = (t < NB && cn > 0) ? atomicAdd(&gcnt[t], cn) : 0;
    __syncthreads();
    cnt[t] = 0;
    __syncthreads();
    // place into LDS ordered buffer (grouped by bucket)
    for (int i = t; i < PCHUNK; i += 512) {
        int e = c0 + i;
        if (e < E) {
            int s = src[e], d = dst[e];
            int k = d >> BSH;
            int slot = scn[k] + atomicAdd(&cnt[k], 1);
            ordered[slot] = (unsigned)s | ((unsigned)(d & 255) << 24);
        }
    }
    __syncthreads();
    // parallel write-out: bucket id = (first k with scn[k] > i) - 1.
    // BUGFIX R14: interval [0,512] holds 513 candidates -> needs 10 iterations
    // (9 left a 1-wide unconverged interval => off-by-one bucket ids, R13 failure).
    int tot = scn[511] + cnt[511];
    for (int i = t; i < tot; i += 512) {
        int lo = 0, hi = 512;
        #pragma unroll
        for (int it = 0; it < 10; ++it) {
            int mid = (lo + hi) >> 1;
            if (scn[mid] > i) hi = mid; else lo = mid + 1;
        }
        int k = lo - 1;
        bucket[(size_t)k * BCAP + gbase[k] + (i - scn[k])] = ordered[i];
    }
}

// ---------- 2. per-bucket: degree count + LDS counting sort -> dense CSR ----------
__global__ __launch_bounds__(256) void sort_k(unsigned* __restrict__ bucket,
                                              const int* __restrict__ gcnt,
                                              int* __restrict__ deg,
                                              float* __restrict__ dinv,
                                              int* __restrict__ off, int n) {
    __shared__ int cnt[256];
    __shared__ int excl[256];
    __shared__ int cur[256];
    __shared__ int ordered[BCAP];            // 35 KB
    int bk = blockIdx.x;
    int t = threadIdx.x;
    int node0 = bk << BSH;
    cnt[t] = 0;
    __syncthreads();
    int ecnt = gcnt[bk];
    unsigned* __restrict__ bb = bucket + (size_t)bk * BCAP;
    for (int i = t; i < ecnt; i += 256) {
        unsigned p = bb[i];
        atomicAdd(&cnt[p >> 24], 1);
    }
    __syncthreads();
    int dg = cnt[t];
    excl[t] = dg;
    __syncthreads();
    for (int o = 1; o < 256; o <<= 1) {
        int v = (t >= o) ? excl[t - o] : 0;
        __syncthreads();
        excl[t] += v;
        __syncthreads();
    }
    int ex = excl[t] - dg;                   // exclusive
    __syncthreads();
    excl[t] = ex;
    cur[t] = 0;
    int node = node0 + t;
    if (node < n) {
        deg[node]  = dg;
        dinv[node] = rsqrtf((float)dg + 1.0f);   // +1 self-loop
        off[node]  = bk * BCAP + ex;             // csr int-index base
    }
    __syncthreads();
    for (int i = t; i < ecnt; i += 256) {
        unsigned p = bb[i];
        int s = (int)(p & 0xFFFFFFu), d = (int)(p >> 24);
        int slot = excl[d] + atomicAdd(&cur[d], 1);
        ordered[slot] = s;
    }
    __syncthreads();
    int* __restrict__ csr = (int*)bb;
    for (int i = t; i < ecnt; i += 256) csr[i] = ordered[i];
}

// ---------- 3. h1' = dinv * (x @ W1) -> fp8 e4m3 ----------
__global__ __launch_bounds__(256) void gemm1_k(const float* __restrict__ x,
                                               const float* __restrict__ W,
                                               const float* __restrict__ dinv,
                                               unsigned char* __restrict__ h, int n) {
    __shared__ float Ws[IN_CH * HID_CH];     // 32 KB
    __shared__ float xs[16][IN_CH];          // 8 KB
    int tid = threadIdx.x;
    for (int i = tid; i < IN_CH * HID_CH; i += 256) Ws[i] = W[i];
    int node0 = blockIdx.x * 16;
    for (int i = tid; i < 16 * IN_CH; i += 256) {
        int nn = i >> 7, k = i & 127;
        int node = node0 + nn;
        xs[nn][k] = (node < n) ? x[(size_t)node * IN_CH + k] : 0.0f;
    }
    __syncthreads();
    int nl = tid >> 6, oc = tid & 63;
    float a0 = 0, a1 = 0, a2 = 0, a3 = 0;
#pragma unroll 8
    for (int k = 0; k < IN_CH; ++k) {
        float w = Ws[k * HID_CH + oc];
        a0 += xs[nl][k] * w;
        a1 += xs[nl + 4][k] * w;
        a2 += xs[nl + 8][k] * w;
        a3 += xs[nl + 12][k] * w;
    }
    int v0 = node0 + nl;
    if (v0      < n) h[(size_t)(v0     ) * HID_CH + oc] = f2fp8(a0 * dinv[v0]);
    if (v0 + 4  < n) h[(size_t)(v0 + 4 ) * HID_CH + oc] = f2fp8(a1 * dinv[v0 + 4]);
    if (v0 + 8  < n) h[(size_t)(v0 + 8 ) * HID_CH + oc] = f2fp8(a2 * dinv[v0 + 8]);
    if (v0 + 12 < n) h[(size_t)(v0 + 12) * HID_CH + oc] = f2fp8(a3 * dinv[v0 + 12]);
}

// ---------- 4. fused layer-1 gather + bias + relu + (z @ W2) * dinv -> h2 fp16 ----------
// wave per node; lane = (edge-slot e8 = lane>>3, channel-group cg = lane&7)
// each lane loads 8 fp8 channels (8B) of one edge -> 1 VMEM covers 8 edges (512B)
__global__ __launch_bounds__(256) void agg1_fused_k(const int* __restrict__ off,
                                                    const int* __restrict__ deg,
                                                    const int* __restrict__ csr,
                                                    const float* __restrict__ dinv,
                                                    const unsigned char* __restrict__ h,
                                                    const float* __restrict__ b1,
                                                    const float* __restrict__ W2,
                                                    __half* __restrict__ h2, int n) {
    __shared__ float Ws2[HID_CH * OUT_CH];   // 2 KB
    __shared__ float sb1[HID_CH];
    int tid = threadIdx.x;
    for (int i = tid; i < HID_CH * OUT_CH; i += 256) Ws2[i] = W2[i];
    if (tid < HID_CH) sb1[tid] = b1[tid];
    __syncthreads();

    int node = blockIdx.x * 4 + (tid >> 6);
    if (node >= n) return;
    int lane = tid & 63;
    int e8 = lane >> 3, cg = lane & 7;

    float acc[8];
#pragma unroll
    for (int j = 0; j < 8; ++j) acc[j] = 0.0f;

    // self-loop row handled by the e8==0 lane group
    if (e8 == 0) {
        ull p = *(const ull*)(h + (size_t)node * HID_CH + cg * 8);
#pragma unroll
        for (int j = 0; j < 8; ++j)
            acc[j] += fp82f((unsigned char)(p >> (8 * j)));
    }

    int o = off[node], end = o + deg[node];
    for (int i = o + e8; i < end; i += 8) {
        int s = csr[i];
        ull p = *(const ull*)(h + (size_t)s * HID_CH + cg * 8);
#pragma unroll
        for (int j = 0; j < 8; ++j)
            acc[j] += fp82f((unsigned char)(p >> (8 * j)));
    }

    // reduce across edge-slots (lanes with same cg): xor 8,16,32
#pragma unroll
    for (int j = 0; j < 8; ++j) {
        acc[j] += __shfl_xor(acc[j], 8);
        acc[j] += __shfl_xor(acc[j], 16);
        acc[j] += __shfl_xor(acc[j], 32);
    }

    // z = relu(dv * acc + b1)  (each lane owns channels cg*8..cg*8+7)
    float dv = dinv[node];
    float z[8];
#pragma unroll
    for (int j = 0; j < 8; ++j)
        z[j] = fmaxf(dv * acc[j] + sb1[cg * 8 + j], 0.0f);

    // partial z @ W2 over this lane's 8 k-rows
    float out[8];
#pragma unroll
    for (int c = 0; c < 8; ++c) out[c] = 0.0f;
#pragma unroll
    for (int j = 0; j < 8; ++j) {
        const float4* row = (const float4*)&Ws2[(cg * 8 + j) * OUT_CH];
        float4 wa = row[0], wb = row[1];
        float zj = z[j];
        out[0] += zj * wa.x; out[1] += zj * wa.y;
        out[2] += zj * wa.z; out[3] += zj * wa.w;
        out[4] += zj * wb.x; out[5] += zj * wb.y;
        out[6] += zj * wb.z; out[7] += zj * wb.w;
    }
    // reduce across cg (xor 1,2,4)
#pragma unroll
    for (int c = 0; c < 8; ++c) {
        out[c] += __shfl_xor(out[c], 1);
        out[c] += __shfl_xor(out[c], 2);
        out[c] += __shfl_xor(out[c], 4);
    }

    if (lane == 0) {
        union { __half2 h2v[4]; uint4 u; } pk;
#pragma unroll
        for (int c2 = 0; c2 < 4; ++c2)
            pk.h2v[c2] = __floats2half2_rn(dv * out[2 * c2], dv * out[2 * c2 + 1]);
        *(uint4*)(h2 + (size_t)node * OUT_CH) = pk.u;
    }
}

// ---------- 5. layer-2 gather (fp16, 4-way) + bias + log_softmax ----------
__global__ __launch_bounds__(256) void agg2_final_k(const int* __restrict__ off,
                                                    const int* __restrict__ deg,
                                                    const int* __restrict__ csr,
                                                    const float* __restrict__ dinv,
                                                    const __half* __restrict__ h2,
                                                    const float* __restrict__ b,
                                                    float* __restrict__ out, int n) {
    int tid = threadIdx.x;
    int node = blockIdx.x * 32 + (tid >> 3);
    int c = tid & 7;
    if (node >= n) return;
    float dv = dinv[node];
    int o = off[node], dg = deg[node];
    float a0 = 0, a1 = 0, a2 = 0, a3 = 0;
    int i = o, end = o + dg;
    for (; i + 3 < end; i += 4) {
        int s0 = csr[i], s1 = csr[i + 1], s2 = csr[i + 2], s3 = csr[i + 3];
        a0 += __half2float(h2[(size_t)s0 * OUT_CH + c]);
        a1 += __half2float(h2[(size_t)s1 * OUT_CH + c]);
        a2 += __half2float(h2[(size_t)s2 * OUT_CH + c]);
        a3 += __half2float(h2[(size_t)s3 * OUT_CH + c]);
    }
    for (; i < end; ++i) a0 += __half2float(h2[(size_t)csr[i] * OUT_CH + c]);
    float self = __half2float(h2[(size_t)node * OUT_CH + c]);
    float val = dv * ((a0 + a1) + (a2 + a3) + self) + b[c];
    float m = val;
    m = fmaxf(m, __shfl_xor(m, 1, 8));
    m = fmaxf(m, __shfl_xor(m, 2, 8));
    m = fmaxf(m, __shfl_xor(m, 4, 8));
    float s8 = expf(val - m);
    s8 += __shfl_xor(s8, 1, 8);
    s8 += __shfl_xor(s8, 2, 8);
    s8 += __shfl_xor(s8, 4, 8);
    out[(size_t)node * OUT_CH + c] = val - m - logf(s8);
}

extern "C" void kernel_launch(void* const* d_in, const int* in_sizes, int n_in,
                              void* d_out, int out_size, void* d_ws, size_t ws_size,
                              hipStream_t stream) {
    const float* x  = (const float*)d_in[0];
    const int*   ei = (const int*)d_in[1];
    const float* W1 = (const float*)d_in[2];
    const float* b1 = (const float*)d_in[3];
    const float* W2 = (const float*)d_in[4];
    const float* b2 = (const float*)d_in[5];
    float* out = (float*)d_out;

    const int n = in_sizes[0] / IN_CH;      // 100000
    const int E = in_sizes[1] / 2;          // 3200000
    const int NP = 100352;
    const int NB = (n + 255) >> BSH;        // 391 buckets

    // ---- workspace layout (~23 MB) ----
    int*      deg    = (int*)d_ws;                              // [NP]
    float*    dinv   = (float*)(deg + NP);                      // [NP]
    int*      gcnt   = (int*)(dinv + NP);                       // [512]
    int*      off    = gcnt + 512;                              // [NP]
    unsigned* bucket = (unsigned*)(off + NP);                   // [NB*BCAP] u32 = 14 MB
    unsigned char* h1 = (unsigned char*)(bucket + (size_t)NB * BCAP); // [NP*64] fp8
    __half*   h2     = (__half*)(h1 + (size_t)NP * HID_CH);     // [NP*8] fp16
    int*      csr    = (int*)bucket;                            // sorted src ids after sort_k

    const int NCH = (E + PCHUNK - 1) / PCHUNK;                  // 391 partition blocks

    hipMemsetAsync(gcnt, 0, 512 * sizeof(int), stream);
    part_k<<<NCH, 512, 0, stream>>>(ei, E, NB, gcnt, bucket);
    sort_k<<<NB, 256, 0, stream>>>(bucket, gcnt, deg, dinv, off, n);
    gemm1_k<<<(n + 15) / 16, 256, 0, stream>>>(x, W1, dinv, h1, n);
    agg1_fused_k<<<(n + 3) / 4, 256, 0, stream>>>(off, deg, csr, dinv, h1, b1, W2, h2, n);
    agg2_final_k<<<(n + 31) / 32, 256, 0, stream>>>(off, deg, csr, dinv, h2, b2, out, n);
}

// Round 15
// 204.577 us; speedup vs baseline: 1.4832x; 1.4832x over previous
//
#include <hip/hip_runtime.h>
#include <hip/hip_fp16.h>
#include <hip/hip_fp8.h>

#define IN_CH  128
#define HID_CH 64
#define OUT_CH 8
#define BSH    8        // 256 nodes per bucket
#define BCAP   8960     // per-bucket edge capacity
#define PCHUNK 8192     // edges per partition block

typedef unsigned long long ull;
typedef float floatx2 __attribute__((ext_vector_type(2)));

// edge_index arrives as int32. src = ei[0..E), dst = ei[E..2E).
// packed edge: low bits = src, bits 24..31 = dst & 255

__device__ __forceinline__ unsigned char f2fp8(float f) {
    __hip_fp8_e4m3 t(f);
    return (unsigned char)t.__x;
}
__device__ __forceinline__ float fp82f(unsigned char b) {
    __hip_fp8_e4m3 t;
    t.__x = (__hip_fp8_storage_t)b;
    return (float)t;
}

// unpack 8 fp8 bytes -> 8 floats via packed HW converts (4 instrs)
__device__ __forceinline__ void acc8(float* acc, ull p) {
#if __has_builtin(__builtin_amdgcn_cvt_pk_f32_fp8)
    unsigned lo = (unsigned)p, hi = (unsigned)(p >> 32);
    floatx2 q0 = __builtin_amdgcn_cvt_pk_f32_fp8(lo, false);
    floatx2 q1 = __builtin_amdgcn_cvt_pk_f32_fp8(lo, true);
    floatx2 q2 = __builtin_amdgcn_cvt_pk_f32_fp8(hi, false);
    floatx2 q3 = __builtin_amdgcn_cvt_pk_f32_fp8(hi, true);
    acc[0] += q0.x; acc[1] += q0.y; acc[2] += q1.x; acc[3] += q1.y;
    acc[4] += q2.x; acc[5] += q2.y; acc[6] += q3.x; acc[7] += q3.y;
#else
#pragma unroll
    for (int j = 0; j < 8; ++j) acc[j] += fp82f((unsigned char)(p >> (8 * j)));
#endif
}

// ---------- 1. coarse partition into 256-node buckets (dense-run writes) ----------
__global__ __launch_bounds__(512) void part_k(const int* __restrict__ ei, int E, int NB,
                                              int* __restrict__ gcnt,
                                              unsigned* __restrict__ bucket) {
    __shared__ int cnt[512];
    __shared__ int scn[512];
    __shared__ int gbase[512];
    __shared__ unsigned ordered[PCHUNK];    // 32 KB
    int t = threadIdx.x;
    int c0 = blockIdx.x * PCHUNK;
    const int* __restrict__ src = ei;
    const int* __restrict__ dst = ei + E;

    cnt[t] = 0;
    __syncthreads();
    for (int i = t; i < PCHUNK; i += 512) {
        int e = c0 + i;
        if (e < E) atomicAdd(&cnt[dst[e] >> BSH], 1);
    }
    __syncthreads();
    scn[t] = cnt[t];
    __syncthreads();
    for (int o = 1; o < 512; o <<= 1) {
        int v = (t >= o) ? scn[t - o] : 0;
        __syncthreads();
        scn[t] += v;
        __syncthreads();
    }
    int ex = scn[t] - cnt[t];
    __syncthreads();
    scn[t] = ex;                             // exclusive scan
    int cn = cnt[t];
    gbase[t] = (t < NB && cn > 0) ? atomicAdd(&gcnt[t], cn) : 0;
    __syncthreads();
    cnt[t] = 0;
    __syncthreads();
    for (int i = t; i < PCHUNK; i += 512) {
        int e = c0 + i;
        if (e < E) {
            int s = src[e], d = dst[e];
            int k = d >> BSH;
            int slot = scn[k] + atomicAdd(&cnt[k], 1);
            ordered[slot] = (unsigned)s | ((unsigned)(d & 255) << 24);
        }
    }
    __syncthreads();
    // parallel write-out; 513 candidates -> 10 binary-search iterations (R13 lesson)
    int tot = scn[511] + cnt[511];
    for (int i = t; i < tot; i += 512) {
        int lo = 0, hi = 512;
        #pragma unroll
        for (int it = 0; it < 10; ++it) {
            int mid = (lo + hi) >> 1;
            if (scn[mid] > i) hi = mid; else lo = mid + 1;
        }
        int k = lo - 1;
        bucket[(size_t)k * BCAP + gbase[k] + (i - scn[k])] = ordered[i];
    }
}

// ---------- 2. per-bucket: degree count + LDS counting sort -> dense CSR ----------
__global__ __launch_bounds__(256) void sort_k(unsigned* __restrict__ bucket,
                                              const int* __restrict__ gcnt,
                                              int* __restrict__ deg,
                                              float* __restrict__ dinv,
                                              int* __restrict__ off, int n) {
    __shared__ int cnt[256];
    __shared__ int excl[256];
    __shared__ int cur[256];
    __shared__ int ordered[BCAP];            // 35 KB
    int bk = blockIdx.x;
    int t = threadIdx.x;
    int node0 = bk << BSH;
    cnt[t] = 0;
    __syncthreads();
    int ecnt = gcnt[bk];
    unsigned* __restrict__ bb = bucket + (size_t)bk * BCAP;
    for (int i = t; i < ecnt; i += 256) {
        unsigned p = bb[i];
        atomicAdd(&cnt[p >> 24], 1);
    }
    __syncthreads();
    int dg = cnt[t];
    excl[t] = dg;
    __syncthreads();
    for (int o = 1; o < 256; o <<= 1) {
        int v = (t >= o) ? excl[t - o] : 0;
        __syncthreads();
        excl[t] += v;
        __syncthreads();
    }
    int ex = excl[t] - dg;                   // exclusive
    __syncthreads();
    excl[t] = ex;
    cur[t] = 0;
    int node = node0 + t;
    if (node < n) {
        deg[node]  = dg;
        dinv[node] = rsqrtf((float)dg + 1.0f);   // +1 self-loop
        off[node]  = bk * BCAP + ex;             // csr int-index base
    }
    __syncthreads();
    for (int i = t; i < ecnt; i += 256) {
        unsigned p = bb[i];
        int s = (int)(p & 0xFFFFFFu), d = (int)(p >> 24);
        int slot = excl[d] + atomicAdd(&cur[d], 1);
        ordered[slot] = s;
    }
    __syncthreads();
    int* __restrict__ csr = (int*)bb;
    for (int i = t; i < ecnt; i += 256) csr[i] = ordered[i];
}

// ---------- 3. h1' = dinv * (x @ W1) -> fp8 e4m3 ----------
__global__ __launch_bounds__(256) void gemm1_k(const float* __restrict__ x,
                                               const float* __restrict__ W,
                                               const float* __restrict__ dinv,
                                               unsigned char* __restrict__ h, int n) {
    __shared__ float Ws[IN_CH * HID_CH];     // 32 KB
    __shared__ float xs[16][IN_CH];          // 8 KB
    int tid = threadIdx.x;
    for (int i = tid; i < IN_CH * HID_CH; i += 256) Ws[i] = W[i];
    int node0 = blockIdx.x * 16;
    for (int i = tid; i < 16 * IN_CH; i += 256) {
        int nn = i >> 7, k = i & 127;
        int node = node0 + nn;
        xs[nn][k] = (node < n) ? x[(size_t)node * IN_CH + k] : 0.0f;
    }
    __syncthreads();
    int nl = tid >> 6, oc = tid & 63;
    float a0 = 0, a1 = 0, a2 = 0, a3 = 0;
#pragma unroll 8
    for (int k = 0; k < IN_CH; ++k) {
        float w = Ws[k * HID_CH + oc];
        a0 += xs[nl][k] * w;
        a1 += xs[nl + 4][k] * w;
        a2 += xs[nl + 8][k] * w;
        a3 += xs[nl + 12][k] * w;
    }
    int v0 = node0 + nl;
    if (v0      < n) h[(size_t)(v0     ) * HID_CH + oc] = f2fp8(a0 * dinv[v0]);
    if (v0 + 4  < n) h[(size_t)(v0 + 4 ) * HID_CH + oc] = f2fp8(a1 * dinv[v0 + 4]);
    if (v0 + 8  < n) h[(size_t)(v0 + 8 ) * HID_CH + oc] = f2fp8(a2 * dinv[v0 + 8]);
    if (v0 + 12 < n) h[(size_t)(v0 + 12) * HID_CH + oc] = f2fp8(a3 * dinv[v0 + 12]);
}

// ---------- 4. layer-1 gather: wide loads + 4-deep unroll -> z fp16 ----------
// wave per node; lane = (e8 = lane>>3 edge slot, cg = lane&7 channel group).
// One VMEM instr = 8 edges x 64B row-slices; 4 unrolled => 32 edges in flight.
__global__ __launch_bounds__(256) void agg1_gather_k(const int* __restrict__ off,
                                                     const int* __restrict__ deg,
                                                     const int* __restrict__ csr,
                                                     const float* __restrict__ dinv,
                                                     const unsigned char* __restrict__ h,
                                                     const float* __restrict__ b1,
                                                     __half* __restrict__ z, int n) {
    int tid = threadIdx.x;
    int node = blockIdx.x * 4 + (tid >> 6);
    if (node >= n) return;
    int lane = tid & 63;
    int e8 = lane >> 3, cg = lane & 7;

    float acc[8];
#pragma unroll
    for (int j = 0; j < 8; ++j) acc[j] = 0.0f;

    if (e8 == 0)   // self-loop row
        acc8(acc, *(const ull*)(h + (size_t)node * HID_CH + cg * 8));

    int o = off[node], end = o + deg[node];
    int i = o + e8;
    for (; i + 24 < end; i += 32) {
        int s0 = csr[i], s1 = csr[i + 8], s2 = csr[i + 16], s3 = csr[i + 24];
        ull p0 = *(const ull*)(h + (size_t)s0 * HID_CH + cg * 8);
        ull p1 = *(const ull*)(h + (size_t)s1 * HID_CH + cg * 8);
        ull p2 = *(const ull*)(h + (size_t)s2 * HID_CH + cg * 8);
        ull p3 = *(const ull*)(h + (size_t)s3 * HID_CH + cg * 8);
        acc8(acc, p0); acc8(acc, p1); acc8(acc, p2); acc8(acc, p3);
    }
    for (; i < end; i += 8)
        acc8(acc, *(const ull*)(h + (size_t)csr[i] * HID_CH + cg * 8));

    // reduce across edge-slots (same cg): xor 8,16,32
#pragma unroll
    for (int j = 0; j < 8; ++j) {
        acc[j] += __shfl_xor(acc[j], 8);
        acc[j] += __shfl_xor(acc[j], 16);
        acc[j] += __shfl_xor(acc[j], 32);
    }

    if (e8 == 0) {
        float dv = dinv[node];
        union { __half2 hv[4]; uint4 u; } pk;
#pragma unroll
        for (int j2 = 0; j2 < 4; ++j2) {
            float z0 = fmaxf(dv * acc[2 * j2]     + b1[cg * 8 + 2 * j2],     0.0f);
            float z1v = fmaxf(dv * acc[2 * j2 + 1] + b1[cg * 8 + 2 * j2 + 1], 0.0f);
            pk.hv[j2] = __floats2half2_rn(z0, z1v);
        }
        *(uint4*)(z + (size_t)node * HID_CH + cg * 8) = pk.u;
    }
}

// ---------- 5. h2' = dinv * (z @ W2) -> fp16 ----------
__global__ __launch_bounds__(256) void gemm2_k(const __half* __restrict__ z,
                                               const float* __restrict__ W,
                                               const float* __restrict__ dinv,
                                               __half* __restrict__ h2, int n) {
    __shared__ float Ws[HID_CH * OUT_CH];
    int tid = threadIdx.x;
    for (int i = tid; i < HID_CH * OUT_CH; i += 256) Ws[i] = W[i];
    __syncthreads();
    int node = blockIdx.x * 256 + tid;
    if (node >= n) return;
    float acc[OUT_CH];
#pragma unroll
    for (int c = 0; c < OUT_CH; ++c) acc[c] = 0.0f;
    const __half2* zr = (const __half2*)(z + (size_t)node * HID_CH);
#pragma unroll 8
    for (int k2 = 0; k2 < HID_CH / 2; ++k2) {
        float2 v = __half22float2(zr[k2]);
        int k = k2 * 2;
#pragma unroll
        for (int c = 0; c < OUT_CH; ++c)
            acc[c] += v.x * Ws[k * OUT_CH + c] + v.y * Ws[(k + 1) * OUT_CH + c];
    }
    float dv = dinv[node];
    __half2* o2 = (__half2*)(h2 + (size_t)node * OUT_CH);
#pragma unroll
    for (int c2 = 0; c2 < OUT_CH / 2; ++c2)
        o2[c2] = __floats2half2_rn(dv * acc[2 * c2], dv * acc[2 * c2 + 1]);
}

// ---------- 6. layer-2 gather (fp16, 4-way) + bias + log_softmax ----------
__global__ __launch_bounds__(256) void agg2_final_k(const int* __restrict__ off,
                                                    const int* __restrict__ deg,
                                                    const int* __restrict__ csr,
                                                    const float* __restrict__ dinv,
                                                    const __half* __restrict__ h2,
                                                    const float* __restrict__ b,
                                                    float* __restrict__ out, int n) {
    int tid = threadIdx.x;
    int node = blockIdx.x * 32 + (tid >> 3);
    int c = tid & 7;
    if (node >= n) return;
    float dv = dinv[node];
    int o = off[node], dg = deg[node];
    float a0 = 0, a1 = 0, a2 = 0, a3 = 0;
    int i = o, end = o + dg;
    for (; i + 3 < end; i += 4) {
        int s0 = csr[i], s1 = csr[i + 1], s2 = csr[i + 2], s3 = csr[i + 3];
        a0 += __half2float(h2[(size_t)s0 * OUT_CH + c]);
        a1 += __half2float(h2[(size_t)s1 * OUT_CH + c]);
        a2 += __half2float(h2[(size_t)s2 * OUT_CH + c]);
        a3 += __half2float(h2[(size_t)s3 * OUT_CH + c]);
    }
    for (; i < end; ++i) a0 += __half2float(h2[(size_t)csr[i] * OUT_CH + c]);
    float self = __half2float(h2[(size_t)node * OUT_CH + c]);
    float val = dv * ((a0 + a1) + (a2 + a3) + self) + b[c];
    float m = val;
    m = fmaxf(m, __shfl_xor(m, 1, 8));
    m = fmaxf(m, __shfl_xor(m, 2, 8));
    m = fmaxf(m, __shfl_xor(m, 4, 8));
    float s8 = expf(val - m);
    s8 += __shfl_xor(s8, 1, 8);
    s8 += __shfl_xor(s8, 2, 8);
    s8 += __shfl_xor(s8, 4, 8);
    out[(size_t)node * OUT_CH + c] = val - m - logf(s8);
}

extern "C" void kernel_launch(void* const* d_in, const int* in_sizes, int n_in,
                              void* d_out, int out_size, void* d_ws, size_t ws_size,
                              hipStream_t stream) {
    const float* x  = (const float*)d_in[0];
    const int*   ei = (const int*)d_in[1];
    const float* W1 = (const float*)d_in[2];
    const float* b1 = (const float*)d_in[3];
    const float* W2 = (const float*)d_in[4];
    const float* b2 = (const float*)d_in[5];
    float* out = (float*)d_out;

    const int n = in_sizes[0] / IN_CH;      // 100000
    const int E = in_sizes[1] / 2;          // 3200000
    const int NP = 100352;
    const int NB = (n + 255) >> BSH;        // 391 buckets

    // ---- workspace layout (~36 MB) ----
    int*      deg    = (int*)d_ws;                              // [NP]
    float*    dinv   = (float*)(deg + NP);                      // [NP]
    int*      gcnt   = (int*)(dinv + NP);                       // [512]
    int*      off    = gcnt + 512;                              // [NP]
    unsigned* bucket = (unsigned*)(off + NP);                   // [NB*BCAP] u32 = 14 MB
    unsigned char* h1 = (unsigned char*)(bucket + (size_t)NB * BCAP); // [NP*64] fp8
    __half*   z1     = (__half*)(h1 + (size_t)NP * HID_CH);     // [NP*64] fp16
    __half*   h2     = z1 + (size_t)NP * HID_CH;                // [NP*8] fp16
    int*      csr    = (int*)bucket;                            // sorted src ids after sort_k

    const int NCH = (E + PCHUNK - 1) / PCHUNK;                  // 391 partition blocks

    hipMemsetAsync(gcnt, 0, 512 * sizeof(int), stream);
    part_k<<<NCH, 512, 0, stream>>>(ei, E, NB, gcnt, bucket);
    sort_k<<<NB, 256, 0, stream>>>(bucket, gcnt, deg, dinv, off, n);
    gemm1_k<<<(n + 15) / 16, 256, 0, stream>>>(x, W1, dinv, h1, n);
    agg1_gather_k<<<(n + 3) / 4, 256, 0, stream>>>(off, deg, csr, dinv, h1, b1, z1, n);
    gemm2_k<<<(n + 255) / 256, 256, 0, stream>>>(z1, W2, dinv, h2, n);
    agg2_final_k<<<(n + 31) / 32, 256, 0, stream>>>(off, deg, csr, dinv, h2, b2, out, n);
}

// Round 16
// 166.177 us; speedup vs baseline: 1.8259x; 1.2311x over previous
//
#include <hip/hip_runtime.h>
#include <hip/hip_fp16.h>
#include <hip/hip_fp8.h>

#define IN_CH  128
#define HID_CH 64
#define OUT_CH 8
#define BSH    8        // 256 nodes per bucket
#define BCAP   8960     // per-bucket edge capacity
#define PCHUNK 8192     // edges per partition block
#define LDK    136      // padded f16 row length (16B-aligned rows, 2-way max conflict)

typedef unsigned long long ull;
typedef float floatx2 __attribute__((ext_vector_type(2)));
typedef _Float16 f16x8 __attribute__((ext_vector_type(8)));
typedef float f32x4 __attribute__((ext_vector_type(4)));

// edge_index arrives as int32. src = ei[0..E), dst = ei[E..2E).
// packed edge: low bits = src, bits 24..31 = dst & 255

__device__ __forceinline__ unsigned char f2fp8(float f) {
    __hip_fp8_e4m3 t(f);
    return (unsigned char)t.__x;
}
__device__ __forceinline__ float fp82f(unsigned char b) {
    __hip_fp8_e4m3 t;
    t.__x = (__hip_fp8_storage_t)b;
    return (float)t;
}

// unpack 8 fp8 bytes -> 8 floats via packed HW converts
__device__ __forceinline__ void acc8(float* acc, ull p) {
#if __has_builtin(__builtin_amdgcn_cvt_pk_f32_fp8)
    unsigned lo = (unsigned)p, hi = (unsigned)(p >> 32);
    floatx2 q0 = __builtin_amdgcn_cvt_pk_f32_fp8(lo, false);
    floatx2 q1 = __builtin_amdgcn_cvt_pk_f32_fp8(lo, true);
    floatx2 q2 = __builtin_amdgcn_cvt_pk_f32_fp8(hi, false);
    floatx2 q3 = __builtin_amdgcn_cvt_pk_f32_fp8(hi, true);
    acc[0] += q0.x; acc[1] += q0.y; acc[2] += q1.x; acc[3] += q1.y;
    acc[4] += q2.x; acc[5] += q2.y; acc[6] += q3.x; acc[7] += q3.y;
#else
#pragma unroll
    for (int j = 0; j < 8; ++j) acc[j] += fp82f((unsigned char)(p >> (8 * j)));
#endif
}

// ---------- 1. coarse partition into 256-node buckets (dense-run writes) ----------
__global__ __launch_bounds__(512) void part_k(const int* __restrict__ ei, int E, int NB,
                                              int* __restrict__ gcnt,
                                              unsigned* __restrict__ bucket) {
    __shared__ int cnt[512];
    __shared__ int scn[512];
    __shared__ int gbase[512];
    __shared__ unsigned ordered[PCHUNK];    // 32 KB
    int t = threadIdx.x;
    int c0 = blockIdx.x * PCHUNK;
    const int* __restrict__ src = ei;
    const int* __restrict__ dst = ei + E;

    cnt[t] = 0;
    __syncthreads();
    for (int i = t; i < PCHUNK; i += 512) {
        int e = c0 + i;
        if (e < E) atomicAdd(&cnt[dst[e] >> BSH], 1);
    }
    __syncthreads();
    scn[t] = cnt[t];
    __syncthreads();
    for (int o = 1; o < 512; o <<= 1) {
        int v = (t >= o) ? scn[t - o] : 0;
        __syncthreads();
        scn[t] += v;
        __syncthreads();
    }
    int ex = scn[t] - cnt[t];
    __syncthreads();
    scn[t] = ex;                             // exclusive scan
    int cn = cnt[t];
    gbase[t] = (t < NB && cn > 0) ? atomicAdd(&gcnt[t], cn) : 0;
    __syncthreads();
    cnt[t] = 0;
    __syncthreads();
    for (int i = t; i < PCHUNK; i += 512) {
        int e = c0 + i;
        if (e < E) {
            int s = src[e], d = dst[e];
            int k = d >> BSH;
            int slot = scn[k] + atomicAdd(&cnt[k], 1);
            ordered[slot] = (unsigned)s | ((unsigned)(d & 255) << 24);
        }
    }
    __syncthreads();
    // parallel write-out; 513 candidates -> 10 binary-search iterations (R13 lesson)
    int tot = scn[511] + cnt[511];
    for (int i = t; i < tot; i += 512) {
        int lo = 0, hi = 512;
        #pragma unroll
        for (int it = 0; it < 10; ++it) {
            int mid = (lo + hi) >> 1;
            if (scn[mid] > i) hi = mid; else lo = mid + 1;
        }
        int k = lo - 1;
        bucket[(size_t)k * BCAP + gbase[k] + (i - scn[k])] = ordered[i];
    }
}

// ---------- 2. per-bucket: degree count + LDS counting sort -> dense CSR ----------
__global__ __launch_bounds__(256) void sort_k(unsigned* __restrict__ bucket,
                                              const int* __restrict__ gcnt,
                                              int* __restrict__ deg,
                                              float* __restrict__ dinv,
                                              int* __restrict__ off, int n) {
    __shared__ int cnt[256];
    __shared__ int excl[256];
    __shared__ int cur[256];
    __shared__ int ordered[BCAP];            // 35 KB
    int bk = blockIdx.x;
    int t = threadIdx.x;
    int node0 = bk << BSH;
    cnt[t] = 0;
    __syncthreads();
    int ecnt = gcnt[bk];
    unsigned* __restrict__ bb = bucket + (size_t)bk * BCAP;
    for (int i = t; i < ecnt; i += 256) {
        unsigned p = bb[i];
        atomicAdd(&cnt[p >> 24], 1);
    }
    __syncthreads();
    int dg = cnt[t];
    excl[t] = dg;
    __syncthreads();
    for (int o = 1; o < 256; o <<= 1) {
        int v = (t >= o) ? excl[t - o] : 0;
        __syncthreads();
        excl[t] += v;
        __syncthreads();
    }
    int ex = excl[t] - dg;                   // exclusive
    __syncthreads();
    excl[t] = ex;
    cur[t] = 0;
    int node = node0 + t;
    if (node < n) {
        deg[node]  = dg;
        dinv[node] = rsqrtf((float)dg + 1.0f);   // +1 self-loop
        off[node]  = bk * BCAP + ex;             // csr int-index base
    }
    __syncthreads();
    for (int i = t; i < ecnt; i += 256) {
        unsigned p = bb[i];
        int s = (int)(p & 0xFFFFFFu), d = (int)(p >> 24);
        int slot = excl[d] + atomicAdd(&cur[d], 1);
        ordered[slot] = s;
    }
    __syncthreads();
    int* __restrict__ csr = (int*)bb;
    for (int i = t; i < ecnt; i += 256) csr[i] = ordered[i];
}

// ---------- 3. h1' = dinv * (x @ W1) -> fp8, via MFMA f16 ----------
// block = 64 nodes; 4 waves, wave w owns rows 16w..16w+16; K=128 in 4 steps.
// A/B frags: 8 contiguous f16 along K (B^T layout, m92 pattern).
// C/D: col=lane&15, row=(lane>>4)*4+r (m89-verified, dtype-independent).
__global__ __launch_bounds__(256) void gemm1_k(const float* __restrict__ x,
                                               const float* __restrict__ W,
                                               const float* __restrict__ dinv,
                                               unsigned char* __restrict__ h, int n) {
    __shared__ __align__(16) float uShared[64 * 68];   // 17408 B: xs f16 overlay, then outS f32
    __shared__ __align__(16) _Float16 Wt[64 * LDK];    // 17408 B: W^T f16
    int t = threadIdx.x;
    int node0 = blockIdx.x * 64;
    _Float16* xs = (_Float16*)uShared;

    // stage x tile: 64 rows x 128 cols fp32 -> f16 (coalesced float4 loads)
    for (int i = t; i < 64 * 32; i += 256) {
        int row = i >> 5, c4 = i & 31;
        int node = node0 + row;
        float4 v = (node < n) ? *(const float4*)(x + (size_t)node * IN_CH + c4 * 4)
                              : make_float4(0.f, 0.f, 0.f, 0.f);
        _Float16* dstp = xs + row * LDK + c4 * 4;
        dstp[0] = (_Float16)v.x; dstp[1] = (_Float16)v.y;
        dstp[2] = (_Float16)v.z; dstp[3] = (_Float16)v.w;
    }
    // stage W^T: W[k][nn] -> Wt[nn][k]
    for (int i = t; i < IN_CH * HID_CH; i += 256) {
        int k = i >> 6, nn = i & 63;
        Wt[nn * LDK + k] = (_Float16)W[i];
    }
    __syncthreads();

    int w = t >> 6, lane = t & 63;
    int rsel = lane & 15, ksel = lane >> 4;   // ksel picks 8-wide k-chunk
    f32x4 acc[4];
#pragma unroll
    for (int ct = 0; ct < 4; ++ct) acc[ct] = (f32x4){0.f, 0.f, 0.f, 0.f};

#pragma unroll
    for (int kk = 0; kk < 4; ++kk) {
        f16x8 a = *(const f16x8*)(xs + (16 * w + rsel) * LDK + kk * 32 + ksel * 8);
#pragma unroll
        for (int ct = 0; ct < 4; ++ct) {
            f16x8 b = *(const f16x8*)(Wt + (ct * 16 + rsel) * LDK + kk * 32 + ksel * 8);
            acc[ct] = __builtin_amdgcn_mfma_f32_16x16x32_f16(a, b, acc[ct], 0, 0, 0);
        }
    }
    __syncthreads();                       // xs dead; overlay outS
    float* outS = uShared;
#pragma unroll
    for (int ct = 0; ct < 4; ++ct)
#pragma unroll
        for (int r = 0; r < 4; ++r)
            outS[(16 * w + ksel * 4 + r) * 68 + ct * 16 + rsel] = acc[ct][r];
    __syncthreads();

    // epilogue: dinv-scale -> fp8, coalesced 16B stores (4 threads per row)
    {
        int row = t >> 2, quad = t & 3;
        int node = node0 + row;
        if (node < n) {
            float dv = dinv[node];
            const float* srcp = outS + row * 68 + quad * 16;
            unsigned un[4];
#pragma unroll
            for (int g = 0; g < 4; ++g) {
                unsigned v = 0;
#pragma unroll
                for (int j = 0; j < 4; ++j)
                    v |= (unsigned)f2fp8(srcp[g * 4 + j] * dv) << (8 * j);
                un[g] = v;
            }
            *(uint4*)(h + (size_t)node * HID_CH + quad * 16) = make_uint4(un[0], un[1], un[2], un[3]);
        }
    }
}

// ---------- 4. layer-1 gather: wide loads + 4-deep unroll -> z fp16 ----------
__global__ __launch_bounds__(256) void agg1_gather_k(const int* __restrict__ off,
                                                     const int* __restrict__ deg,
                                                     const int* __restrict__ csr,
                                                     const float* __restrict__ dinv,
                                                     const unsigned char* __restrict__ h,
                                                     const float* __restrict__ b1,
                                                     __half* __restrict__ z, int n) {
    int tid = threadIdx.x;
    int node = blockIdx.x * 4 + (tid >> 6);
    if (node >= n) return;
    int lane = tid & 63;
    int e8 = lane >> 3, cg = lane & 7;

    float acc[8];
#pragma unroll
    for (int j = 0; j < 8; ++j) acc[j] = 0.0f;

    if (e8 == 0)   // self-loop row
        acc8(acc, *(const ull*)(h + (size_t)node * HID_CH + cg * 8));

    int o = off[node], end = o + deg[node];
    int i = o + e8;
    for (; i + 24 < end; i += 32) {
        int s0 = csr[i], s1 = csr[i + 8], s2 = csr[i + 16], s3 = csr[i + 24];
        ull p0 = *(const ull*)(h + (size_t)s0 * HID_CH + cg * 8);
        ull p1 = *(const ull*)(h + (size_t)s1 * HID_CH + cg * 8);
        ull p2 = *(const ull*)(h + (size_t)s2 * HID_CH + cg * 8);
        ull p3 = *(const ull*)(h + (size_t)s3 * HID_CH + cg * 8);
        acc8(acc, p0); acc8(acc, p1); acc8(acc, p2); acc8(acc, p3);
    }
    for (; i < end; i += 8)
        acc8(acc, *(const ull*)(h + (size_t)csr[i] * HID_CH + cg * 8));

#pragma unroll
    for (int j = 0; j < 8; ++j) {
        acc[j] += __shfl_xor(acc[j], 8);
        acc[j] += __shfl_xor(acc[j], 16);
        acc[j] += __shfl_xor(acc[j], 32);
    }

    if (e8 == 0) {
        float dv = dinv[node];
        union { __half2 hv[4]; uint4 u; } pk;
#pragma unroll
        for (int j2 = 0; j2 < 4; ++j2) {
            float z0 = fmaxf(dv * acc[2 * j2]      + b1[cg * 8 + 2 * j2],     0.0f);
            float z1v = fmaxf(dv * acc[2 * j2 + 1] + b1[cg * 8 + 2 * j2 + 1], 0.0f);
            pk.hv[j2] = __floats2half2_rn(z0, z1v);
        }
        *(uint4*)(z + (size_t)node * HID_CH + cg * 8) = pk.u;
    }
}

// ---------- 5. h2' = dinv * (z @ W2) -> fp16 ----------
__global__ __launch_bounds__(256) void gemm2_k(const __half* __restrict__ z,
                                               const float* __restrict__ W,
                                               const float* __restrict__ dinv,
                                               __half* __restrict__ h2, int n) {
    __shared__ float Ws[HID_CH * OUT_CH];
    int tid = threadIdx.x;
    for (int i = tid; i < HID_CH * OUT_CH; i += 256) Ws[i] = W[i];
    __syncthreads();
    int node = blockIdx.x * 256 + tid;
    if (node >= n) return;
    float acc[OUT_CH];
#pragma unroll
    for (int c = 0; c < OUT_CH; ++c) acc[c] = 0.0f;
    const __half2* zr = (const __half2*)(z + (size_t)node * HID_CH);
#pragma unroll 8
    for (int k2 = 0; k2 < HID_CH / 2; ++k2) {
        float2 v = __half22float2(zr[k2]);
        int k = k2 * 2;
#pragma unroll
        for (int c = 0; c < OUT_CH; ++c)
            acc[c] += v.x * Ws[k * OUT_CH + c] + v.y * Ws[(k + 1) * OUT_CH + c];
    }
    float dv = dinv[node];
    __half2* o2 = (__half2*)(h2 + (size_t)node * OUT_CH);
#pragma unroll
    for (int c2 = 0; c2 < OUT_CH / 2; ++c2)
        o2[c2] = __floats2half2_rn(dv * acc[2 * c2], dv * acc[2 * c2 + 1]);
}

// ---------- 6. layer-2 gather (fp16, 4-way) + bias + log_softmax ----------
__global__ __launch_bounds__(256) void agg2_final_k(const int* __restrict__ off,
                                                    const int* __restrict__ deg,
                                                    const int* __restrict__ csr,
                                                    const float* __restrict__ dinv,
                                                    const __half* __restrict__ h2,
                                                    const float* __restrict__ b,
                                                    float* __restrict__ out, int n) {
    int tid = threadIdx.x;
    int node = blockIdx.x * 32 + (tid >> 3);
    int c = tid & 7;
    if (node >= n) return;
    float dv = dinv[node];
    int o = off[node], dg = deg[node];
    float a0 = 0, a1 = 0, a2 = 0, a3 = 0;
    int i = o, end = o + dg;
    for (; i + 3 < end; i += 4) {
        int s0 = csr[i], s1 = csr[i + 1], s2 = csr[i + 2], s3 = csr[i + 3];
        a0 += __half2float(h2[(size_t)s0 * OUT_CH + c]);
        a1 += __half2float(h2[(size_t)s1 * OUT_CH + c]);
        a2 += __half2float(h2[(size_t)s2 * OUT_CH + c]);
        a3 += __half2float(h2[(size_t)s3 * OUT_CH + c]);
    }
    for (; i < end; ++i) a0 += __half2float(h2[(size_t)csr[i] * OUT_CH + c]);
    float self = __half2float(h2[(size_t)node * OUT_CH + c]);
    float val = dv * ((a0 + a1) + (a2 + a3) + self) + b[c];
    float m = val;
    m = fmaxf(m, __shfl_xor(m, 1, 8));
    m = fmaxf(m, __shfl_xor(m, 2, 8));
    m = fmaxf(m, __shfl_xor(m, 4, 8));
    float s8 = expf(val - m);
    s8 += __shfl_xor(s8, 1, 8);
    s8 += __shfl_xor(s8, 2, 8);
    s8 += __shfl_xor(s8, 4, 8);
    out[(size_t)node * OUT_CH + c] = val - m - logf(s8);
}

extern "C" void kernel_launch(void* const* d_in, const int* in_sizes, int n_in,
                              void* d_out, int out_size, void* d_ws, size_t ws_size,
                              hipStream_t stream) {
    const float* x  = (const float*)d_in[0];
    const int*   ei = (const int*)d_in[1];
    const float* W1 = (const float*)d_in[2];
    const float* b1 = (const float*)d_in[3];
    const float* W2 = (const float*)d_in[4];
    const float* b2 = (const float*)d_in[5];
    float* out = (float*)d_out;

    const int n = in_sizes[0] / IN_CH;      // 100000
    const int E = in_sizes[1] / 2;          // 3200000
    const int NP = 100352;
    const int NB = (n + 255) >> BSH;        // 391 buckets

    // ---- workspace layout (~36 MB) ----
    int*      deg    = (int*)d_ws;                              // [NP]
    float*    dinv   = (float*)(deg + NP);                      // [NP]
    int*      gcnt   = (int*)(dinv + NP);                       // [512]
    int*      off    = gcnt + 512;                              // [NP]
    unsigned* bucket = (unsigned*)(off + NP);                   // [NB*BCAP] u32 = 14 MB
    unsigned char* h1 = (unsigned char*)(bucket + (size_t)NB * BCAP); // [NP*64] fp8
    __half*   z1     = (__half*)(h1 + (size_t)NP * HID_CH);     // [NP*64] fp16
    __half*   h2     = z1 + (size_t)NP * HID_CH;                // [NP*8] fp16
    int*      csr    = (int*)bucket;                            // sorted src ids after sort_k

    const int NCH = (E + PCHUNK - 1) / PCHUNK;                  // 391 partition blocks

    hipMemsetAsync(gcnt, 0, 512 * sizeof(int), stream);
    part_k<<<NCH, 512, 0, stream>>>(ei, E, NB, gcnt, bucket);
    sort_k<<<NB, 256, 0, stream>>>(bucket, gcnt, deg, dinv, off, n);
    gemm1_k<<<(n + 63) / 64, 256, 0, stream>>>(x, W1, dinv, h1, n);
    agg1_gather_k<<<(n + 3) / 4, 256, 0, stream>>>(off, deg, csr, dinv, h1, b1, z1, n);
    gemm2_k<<<(n + 255) / 256, 256, 0, stream>>>(z1, W2, dinv, h2, n);
    agg2_final_k<<<(n + 31) / 32, 256, 0, stream>>>(off, deg, csr, dinv, h2, b2, out, n);
}